// Round 4
// baseline (172.916 us; speedup 1.0000x reference)
//
#include <hip/hip_runtime.h>
#include <math.h>

// Problem constants
#define B_    2
#define K_    8
#define C_    64
#define CH_   32      // C/2
#define H_    128
#define W_    128
#define HW_   16384   // H*W
#define BN_EPS 1e-5f
#define SIGMA_MAX 0.3f
#define COV_SHRINK 0.1f
#define COV_DELTA 1e-3f

#define TILE_ 32      // pixels per capon_fuse block (one row segment)

// ---------------------------------------------------------------------------
// Kernel 1: sensor maps, c-split wave pairing, inline BN fold (no prep pass).
// Each 64-pixel group is handled by TWO waves: half=0 accumulates c in
// [0,32), half=1 c in [32,64); acc[32] only -> ~50 VGPR, 8 waves/SIMD.
// Raw w1[o][c] is read via wave-uniform scalar loads (8 KB, constant-cache
// resident). BN scale/shift applied in the epilogue: h = inv*sum + beff,
// which matches the reference's scale-after-sum exactly.
// ---------------------------------------------------------------------------
__global__ void __launch_bounds__(256, 8)
stage1_kernel(const float* __restrict__ X,
              const float* __restrict__ w1,        // [32][64] raw
              const float* __restrict__ bn_scale,  // [32]
              const float* __restrict__ bn_bias,   // [32]
              const float* __restrict__ bn_mean,   // [32]
              const float* __restrict__ bn_var,    // [32]
              const float* __restrict__ w2,        // [32]
              float* __restrict__ S) {
    __shared__ float xch[2][64][CH_ + 1];

    int tid  = threadIdx.x;
    int lane = tid & 63;
    int pair = tid >> 7;                 // 0..1 (two pixel groups per block)
    int half = (tid >> 6) & 1;           // 0..1 (c-half)
    int gpx  = blockIdx.x * 128 + pair * 64 + lane;   // global pixel 0..262143
    int bk   = gpx >> 14;
    int hw   = gpx & (HW_ - 1);
    const float* xp = X + (size_t)bk * (C_ * HW_) + hw;
    int cbase = __builtin_amdgcn_readfirstlane(half << 5);

    float acc[CH_];
#pragma unroll
    for (int o = 0; o < CH_; ++o) acc[o] = 0.f;

#pragma unroll 4
    for (int cc = 0; cc < CH_; ++cc) {
        int c = cbase + cc;
        float xv = xp[(size_t)c * HW_];
#pragma unroll
        for (int o = 0; o < CH_; ++o)
            acc[o] = fmaf(w1[o * C_ + c], xv, acc[o]);
    }

    if (half == 1) {
#pragma unroll
        for (int o = 0; o < CH_; ++o) xch[pair][lane][o] = acc[o];
    }
    __syncthreads();
    if (half == 0) {
        float s = 0.f;
#pragma unroll
        for (int o = 0; o < CH_; ++o) {
            float v   = acc[o] + xch[pair][lane][o];
            float inv = bn_scale[o] * rsqrtf(bn_var[o] + BN_EPS);
            float hv  = fmaf(inv, v, fmaf(-bn_mean[o], inv, bn_bias[o]));
            s = fmaf(w2[o], fmaxf(hv, 0.f), s);
        }
        S[gpx] = s;
    }
}

// ---------------------------------------------------------------------------
// Kernel 2: fused capon + fusion, inline guidance params. 1024 blocks x 256
// threads, TILE_=32 pixels (one 32-px row segment, same image row h).
// Stage 0 (all 256 threads): cooperatively load the 8x3x34 reflected S
//   stencil into LDS (coalesced; reflection applied here).
// Phase A (threads 0..31): softmax(a0_raw)/sig2 in-register, patches from
//   LDS -> 8x8 covariance -> diagonal-loaded Cholesky -> normalized w -> LDS.
// Phase B (all 256 threads): Y[b,c,hw] = sum_k w[hw,k] * X[b,k,c,hw];
//   thread = (c8, px), coalesced 128 B segments.
// ---------------------------------------------------------------------------
__global__ void __launch_bounds__(256)
capon_fuse_kernel(const float* __restrict__ X,
                  const float* __restrict__ S,
                  const float* __restrict__ a0_raw,    // [8]
                  const float* __restrict__ sigma_raw, // [8]
                  float* __restrict__ out) {
    __shared__ float sL[K_][3][36];       // 34 used cols, padded
    __shared__ float wL[TILE_][K_ + 1];   // stride 9 -> conflict-free

    int tid    = threadIdx.x;
    int gbase  = blockIdx.x * TILE_;      // global pixel base (0..32767)
    int b      = gbase >> 14;
    int hwbase = gbase & (HW_ - 1);
    int h      = hwbase >> 7;
    int wbase  = hwbase & (W_ - 1);       // 0,32,64,96

    // reflect rows (np.pad 'reflect': -1 -> 1, H -> H-2)
    int hm = (h == 0)      ? 1      : h - 1;
    int hp = (h == H_ - 1) ? H_ - 2 : h + 1;
    int rows[3] = {hm * W_, h * W_, hp * W_};

    // ---- Stage 0: cooperative S-stencil load (8k x 3rows x 34cols = 816)
    for (int idx = tid; idx < K_ * 3 * 34; idx += 256) {
        int k   = idx / 102;
        int rem = idx - k * 102;
        int r   = rem / 34;
        int s   = rem - r * 34;
        int cg  = wbase - 1 + s;                      // -1 .. 128
        cg = (cg < 0) ? 1 : ((cg > W_ - 1) ? W_ - 2 : cg);
        sL[k][r][s] = S[(((size_t)b * K_ + k) << 14) + rows[r] + cg];
    }
    __syncthreads();

    // ---- Phase A: solves (threads 0..31, one pixel each)
    if (tid < TILE_) {
        int px = tid;

        // guidance params in-register (uniform scalar loads, trivial VALU)
        float ar[K_], a0v[K_], sig2v[K_];
#pragma unroll
        for (int k = 0; k < K_; ++k) ar[k] = a0_raw[k];
        float mx = ar[0];
#pragma unroll
        for (int k = 1; k < K_; ++k) mx = fmaxf(mx, ar[k]);
        float sum = 0.f;
#pragma unroll
        for (int k = 0; k < K_; ++k) {
            a0v[k] = expf(ar[k] - mx);
            sum += a0v[k];
        }
        float rsum = 1.f / sum;
#pragma unroll
        for (int k = 0; k < K_; ++k) {
            a0v[k] *= rsum;
            float sg = SIGMA_MAX / (1.f + expf(-sigma_raw[k]));
            sig2v[k] = sg * sg;
        }

        float pc[K_][9];
#pragma unroll
        for (int k = 0; k < K_; ++k) {
            float p[9];
            float m = 0.f;
#pragma unroll
            for (int i = 0; i < 3; ++i)
#pragma unroll
                for (int j = 0; j < 3; ++j) {
                    float v = sL[k][i][px + j];
                    p[i * 3 + j] = v;
                    m += v;
                }
            m *= (1.f / 9.f);
#pragma unroll
            for (int n = 0; n < 9; ++n) pc[k][n] = p[n] - m;
        }

        // A = 0.9*R + (0.1*tr(R)/K + delta)*I + diag(sig2); R[i][j]=pc_i·pc_j/9
        float A[K_][K_];
        float tr = 0.f;
#pragma unroll
        for (int i = 0; i < K_; ++i) {
            float s = 0.f;
#pragma unroll
            for (int n = 0; n < 9; ++n) s = fmaf(pc[i][n], pc[i][n], s);
            s *= (1.f / 9.f);
            tr += s;
            A[i][i] = s;
        }
#pragma unroll
        for (int i = 0; i < K_; ++i)
#pragma unroll
            for (int j = 0; j < i; ++j) {
                float s = 0.f;
#pragma unroll
                for (int n = 0; n < 9; ++n) s = fmaf(pc[i][n], pc[j][n], s);
                A[i][j] = (1.f - COV_SHRINK) * s * (1.f / 9.f);
            }
        float dl = COV_SHRINK * tr * (1.f / (float)K_) + COV_DELTA;
#pragma unroll
        for (int i = 0; i < K_; ++i)
            A[i][i] = (1.f - COV_SHRINK) * A[i][i] + dl + sig2v[i];

        // Cholesky A = L L^T (L overwrites lower triangle)
#pragma unroll
        for (int j = 0; j < K_; ++j) {
            float d = A[j][j];
#pragma unroll
            for (int t = 0; t < j; ++t) d = fmaf(-A[j][t], A[j][t], d);
            d = sqrtf(d);
            A[j][j] = d;
            float inv = 1.f / d;
#pragma unroll
            for (int i = j + 1; i < K_; ++i) {
                float s = A[i][j];
#pragma unroll
                for (int t = 0; t < j; ++t) s = fmaf(-A[i][t], A[j][t], s);
                A[i][j] = s * inv;
            }
        }
        // forward solve L z = a0
        float z[K_];
#pragma unroll
        for (int i = 0; i < K_; ++i) {
            float s = a0v[i];
#pragma unroll
            for (int t = 0; t < i; ++t) s = fmaf(-A[i][t], z[t], s);
            z[i] = s / A[i][i];
        }
        // back solve L^T x = z
        float x[K_];
#pragma unroll
        for (int i = K_ - 1; i >= 0; --i) {
            float s = z[i];
#pragma unroll
            for (int t = i + 1; t < K_; ++t) s = fmaf(-A[t][i], x[t], s);
            x[i] = s / A[i][i];
        }
        float denom = 0.f;
#pragma unroll
        for (int k = 0; k < K_; ++k) denom = fmaf(x[k], a0v[k], denom);
        float invd = 1.f / denom;
#pragma unroll
        for (int k = 0; k < K_; ++k) wL[px][k] = x[k] * invd;
    }
    __syncthreads();

    // ---- Phase B: fusion. thread = (c8, px); px contiguous -> coalesced.
    int px = tid & (TILE_ - 1);
    int c8 = tid >> 5;                   // 0..7
    float wr[K_];
#pragma unroll
    for (int k = 0; k < K_; ++k) wr[k] = wL[px][k];

    const float* xb = X + ((size_t)b * K_ * C_) * HW_ + hwbase + px;
    float* ob = out + ((size_t)b * C_) * HW_ + hwbase + px;
    const size_t kstride = (size_t)C_ * HW_;

#pragma unroll 2
    for (int j = 0; j < C_ / 8; ++j) {
        int c = (j << 3) | c8;
        const float* xp = xb + (size_t)c * HW_;
        float acc = wr[0] * xp[0];
        acc = fmaf(wr[1], xp[kstride * 1], acc);
        acc = fmaf(wr[2], xp[kstride * 2], acc);
        acc = fmaf(wr[3], xp[kstride * 3], acc);
        acc = fmaf(wr[4], xp[kstride * 4], acc);
        acc = fmaf(wr[5], xp[kstride * 5], acc);
        acc = fmaf(wr[6], xp[kstride * 6], acc);
        acc = fmaf(wr[7], xp[kstride * 7], acc);
        ob[(size_t)c * HW_] = acc;
    }
}

// ---------------------------------------------------------------------------
extern "C" void kernel_launch(void* const* d_in, const int* in_sizes, int n_in,
                              void* d_out, int out_size, void* d_ws, size_t ws_size,
                              hipStream_t stream) {
    const float* X         = (const float*)d_in[0];
    const float* w1        = (const float*)d_in[1];
    const float* bn_scale  = (const float*)d_in[2];
    const float* bn_bias   = (const float*)d_in[3];
    const float* bn_mean   = (const float*)d_in[4];
    const float* bn_var    = (const float*)d_in[5];
    const float* w2        = (const float*)d_in[6];
    const float* a0_raw    = (const float*)d_in[7];
    const float* sigma_raw = (const float*)d_in[8];
    float* out = (float*)d_out;
    float* ws  = (float*)d_ws;

    float* S = ws;                         // B*K*HW = 262144 floats

    int n1 = B_ * K_ * HW_ * 2;            // 524288 threads (2 per pixel)
    stage1_kernel<<<n1 / 256, 256, 0, stream>>>(X, w1, bn_scale, bn_bias,
                                                bn_mean, bn_var, w2, S);

    int n2 = B_ * HW_ / TILE_;             // 1024 blocks
    capon_fuse_kernel<<<n2, 256, 0, stream>>>(X, S, a0_raw, sigma_raw, out);
}

// Round 5
// 129.027 us; speedup vs baseline: 1.3402x; 1.3402x over previous
//
#include <hip/hip_runtime.h>
#include <math.h>

// Problem constants
#define B_    2
#define K_    8
#define C_    64
#define CH_   32      // C/2
#define H_    128
#define W_    128
#define HW_   16384   // H*W
#define BN_EPS 1e-5f
#define SIGMA_MAX 0.3f
#define COV_SHRINK 0.1f
#define COV_DELTA 1e-3f

#define TILE_ 32      // pixels per capon_fuse block (one row segment)

// ---------------------------------------------------------------------------
// Kernel 0: fold BN into w1 (TRANSPOSED: wf_t[c][o] contiguous in o so stage1
// can read each c-row with 2x s_load_dwordx16 — this layout is the whole
// point; raw w1[o][c] strided scalar loads cost stage1 5x. Params in ws:
//   [0..2047]     wf_t[c][o] = w1[o][c] * bn_scale[o]/sqrt(var[o]+eps)
//   [2048..2079]  beff[o]    = bn_bias[o] - bn_mean[o]*inv_std[o]
//   [2080..2111]  w2[o]
//   [2112..2119]  a0[k]      = softmax(a0_raw)[k]
//   [2120..2127]  sig2[k]    = (SIGMA_MAX*sigmoid(sigma_raw[k]))^2
// ---------------------------------------------------------------------------
__global__ void prep_kernel(const float* __restrict__ w1,
                            const float* __restrict__ bn_scale,
                            const float* __restrict__ bn_bias,
                            const float* __restrict__ bn_mean,
                            const float* __restrict__ bn_var,
                            const float* __restrict__ w2,
                            const float* __restrict__ a0_raw,
                            const float* __restrict__ sigma_raw,
                            float* __restrict__ par) {
    int t = threadIdx.x;
    for (int i = t; i < CH_ * C_; i += blockDim.x) {
        int c = i >> 5;         // 0..63
        int o = i & 31;         // 0..31
        float inv = bn_scale[o] / sqrtf(bn_var[o] + BN_EPS);
        par[c * CH_ + o] = w1[o * C_ + c] * inv;
    }
    if (t < CH_) {
        float inv = bn_scale[t] / sqrtf(bn_var[t] + BN_EPS);
        par[2048 + t] = bn_bias[t] - bn_mean[t] * inv;
        par[2080 + t] = w2[t];
    }
    if (t < K_) {
        float m = -1e30f;
        for (int i = 0; i < K_; ++i) m = fmaxf(m, a0_raw[i]);
        float s = 0.f;
        for (int i = 0; i < K_; ++i) s += expf(a0_raw[i] - m);
        par[2112 + t] = expf(a0_raw[t] - m) / s;
        float sg = SIGMA_MAX / (1.f + expf(-sigma_raw[t]));
        par[2120 + t] = sg * sg;
    }
}

// ---------------------------------------------------------------------------
// Kernel 1: sensor maps, c-split wave pairing (proven R2/R3 version).
// Each 64-pixel group handled by TWO waves: half=0 sums c in [0,32),
// half=1 sums c in [32,64). acc[32] only -> ~36 VGPR, 8 waves/SIMD (100%).
// half=1 dumps partials to LDS; half=0 adds, ReLU + w2 dot, stores S.
// X read exactly once; weights via contiguous wave-uniform s_loads.
// ---------------------------------------------------------------------------
__global__ void __launch_bounds__(256, 8)
stage1_kernel(const float* __restrict__ X,
              const float* __restrict__ wf,    // [64][32]
              const float* __restrict__ beff,  // [32]
              const float* __restrict__ w2,    // [32]
              float* __restrict__ S) {
    __shared__ float xch[2][64][CH_ + 1];

    int tid  = threadIdx.x;
    int lane = tid & 63;
    int pair = tid >> 7;                 // 0..1 (two pixel groups per block)
    int half = (tid >> 6) & 1;           // 0..1 (c-half)
    int gpx  = blockIdx.x * 128 + pair * 64 + lane;   // global pixel 0..262143
    int bk   = gpx >> 14;
    int hw   = gpx & (HW_ - 1);
    const float* xp = X + (size_t)bk * (C_ * HW_) + hw;
    int cbase = __builtin_amdgcn_readfirstlane(half << 5);

    float acc[CH_];
    if (half == 0) {
#pragma unroll
        for (int o = 0; o < CH_; ++o) acc[o] = beff[o];
    } else {
#pragma unroll
        for (int o = 0; o < CH_; ++o) acc[o] = 0.f;
    }

#pragma unroll 4
    for (int c = 0; c < CH_; ++c) {
        float xv = xp[(size_t)(cbase + c) * HW_];
        const float* wrow = wf + (cbase + c) * CH_;
#pragma unroll
        for (int o = 0; o < CH_; ++o) acc[o] = fmaf(wrow[o], xv, acc[o]);
    }

    if (half == 1) {
#pragma unroll
        for (int o = 0; o < CH_; ++o) xch[pair][lane][o] = acc[o];
    }
    __syncthreads();
    if (half == 0) {
        float s = 0.f;
#pragma unroll
        for (int o = 0; o < CH_; ++o) {
            float v = acc[o] + xch[pair][lane][o];
            s = fmaf(w2[o], fmaxf(v, 0.f), s);
        }
        S[gpx] = s;
    }
}

// ---------------------------------------------------------------------------
// Kernel 2: fused capon + fusion. 1024 blocks x 256 threads, TILE_=32 px.
// Stage 0: cooperative load of the 8x3x34 reflected S stencil into LDS.
// Phase A (threads 0..31): patches from LDS -> 8x8 covariance ->
//   diagonal-loaded Cholesky -> normalized w -> LDS (stride 9).
// Phase B (all 256): thread = (cg 0..15, px2 0..15), 2 px/thread via
//   float2 — halves VMEM instruction count at identical coalescing
//   (each 16-lane group covers 128 B).
// ---------------------------------------------------------------------------
__global__ void __launch_bounds__(256)
capon_fuse_kernel(const float* __restrict__ X,
                  const float* __restrict__ S,
                  const float* __restrict__ a0,    // [8]
                  const float* __restrict__ sig2,  // [8]
                  float* __restrict__ out) {
    __shared__ float sL[K_][3][36];       // 34 used cols, padded
    __shared__ float wL[TILE_][K_ + 1];   // stride 9 -> conflict-free

    int tid    = threadIdx.x;
    int gbase  = blockIdx.x * TILE_;      // global pixel base (0..32767)
    int b      = gbase >> 14;
    int hwbase = gbase & (HW_ - 1);
    int h      = hwbase >> 7;
    int wbase  = hwbase & (W_ - 1);       // 0,32,64,96

    // reflect rows (np.pad 'reflect': -1 -> 1, H -> H-2)
    int hm = (h == 0)      ? 1      : h - 1;
    int hp = (h == H_ - 1) ? H_ - 2 : h + 1;
    int rows[3] = {hm * W_, h * W_, hp * W_};

    // ---- Stage 0: cooperative S-stencil load (8k x 3rows x 34cols = 816)
    for (int idx = tid; idx < K_ * 3 * 34; idx += 256) {
        int k   = idx / 102;
        int rem = idx - k * 102;
        int r   = rem / 34;
        int s   = rem - r * 34;
        int cg  = wbase - 1 + s;                      // -1 .. 128
        cg = (cg < 0) ? 1 : ((cg > W_ - 1) ? W_ - 2 : cg);
        sL[k][r][s] = S[(((size_t)b * K_ + k) << 14) + rows[r] + cg];
    }
    __syncthreads();

    // ---- Phase A: solves (threads 0..31, one pixel each)
    if (tid < TILE_) {
        int px = tid;

        float pc[K_][9];
#pragma unroll
        for (int k = 0; k < K_; ++k) {
            float p[9];
            float m = 0.f;
#pragma unroll
            for (int i = 0; i < 3; ++i)
#pragma unroll
                for (int j = 0; j < 3; ++j) {
                    float v = sL[k][i][px + j];
                    p[i * 3 + j] = v;
                    m += v;
                }
            m *= (1.f / 9.f);
#pragma unroll
            for (int n = 0; n < 9; ++n) pc[k][n] = p[n] - m;
        }

        // A = 0.9*R + (0.1*tr(R)/K + delta)*I + diag(sig2); R[i][j]=pc_i·pc_j/9
        float A[K_][K_];
        float tr = 0.f;
#pragma unroll
        for (int i = 0; i < K_; ++i) {
            float s = 0.f;
#pragma unroll
            for (int n = 0; n < 9; ++n) s = fmaf(pc[i][n], pc[i][n], s);
            s *= (1.f / 9.f);
            tr += s;
            A[i][i] = s;
        }
#pragma unroll
        for (int i = 0; i < K_; ++i)
#pragma unroll
            for (int j = 0; j < i; ++j) {
                float s = 0.f;
#pragma unroll
                for (int n = 0; n < 9; ++n) s = fmaf(pc[i][n], pc[j][n], s);
                A[i][j] = (1.f - COV_SHRINK) * s * (1.f / 9.f);
            }
        float dl = COV_SHRINK * tr * (1.f / (float)K_) + COV_DELTA;
#pragma unroll
        for (int i = 0; i < K_; ++i)
            A[i][i] = (1.f - COV_SHRINK) * A[i][i] + dl + sig2[i];

        // Cholesky A = L L^T (L overwrites lower triangle)
#pragma unroll
        for (int j = 0; j < K_; ++j) {
            float d = A[j][j];
#pragma unroll
            for (int t = 0; t < j; ++t) d = fmaf(-A[j][t], A[j][t], d);
            d = sqrtf(d);
            A[j][j] = d;
            float inv = 1.f / d;
#pragma unroll
            for (int i = j + 1; i < K_; ++i) {
                float s = A[i][j];
#pragma unroll
                for (int t = 0; t < j; ++t) s = fmaf(-A[i][t], A[j][t], s);
                A[i][j] = s * inv;
            }
        }
        // forward solve L z = a0
        float z[K_];
#pragma unroll
        for (int i = 0; i < K_; ++i) {
            float s = a0[i];
#pragma unroll
            for (int t = 0; t < i; ++t) s = fmaf(-A[i][t], z[t], s);
            z[i] = s / A[i][i];
        }
        // back solve L^T x = z
        float x[K_];
#pragma unroll
        for (int i = K_ - 1; i >= 0; --i) {
            float s = z[i];
#pragma unroll
            for (int t = i + 1; t < K_; ++t) s = fmaf(-A[t][i], x[t], s);
            x[i] = s / A[i][i];
        }
        float denom = 0.f;
#pragma unroll
        for (int k = 0; k < K_; ++k) denom = fmaf(x[k], a0[k], denom);
        float invd = 1.f / denom;
#pragma unroll
        for (int k = 0; k < K_; ++k) wL[px][k] = x[k] * invd;
    }
    __syncthreads();

    // ---- Phase B: fusion, 2 px per thread (float2).
    int px2 = tid & 15;                  // pixel pair: pixels 2*px2, 2*px2+1
    int cg  = tid >> 4;                  // 0..15 channel group
    int pA  = px2 * 2;
    int pBx = pA + 1;

    float wa[K_], wb[K_];
#pragma unroll
    for (int k = 0; k < K_; ++k) {
        wa[k] = wL[pA][k];
        wb[k] = wL[pBx][k];
    }

    const float* xb = X + ((size_t)b * K_ * C_) * HW_ + hwbase + pA;
    float* ob = out + ((size_t)b * C_) * HW_ + hwbase + pA;
    const size_t kstride = (size_t)C_ * HW_;

#pragma unroll
    for (int j = 0; j < C_ / 16; ++j) {
        int c = (j << 4) | cg;
        const float* xp = xb + (size_t)c * HW_;
        float accx = 0.f, accy = 0.f;
#pragma unroll
        for (int k = 0; k < K_; ++k) {
            float2 v = *(const float2*)(xp + kstride * k);
            accx = fmaf(wa[k], v.x, accx);
            accy = fmaf(wb[k], v.y, accy);
        }
        *(float2*)(ob + (size_t)c * HW_) = make_float2(accx, accy);
    }
}

// ---------------------------------------------------------------------------
extern "C" void kernel_launch(void* const* d_in, const int* in_sizes, int n_in,
                              void* d_out, int out_size, void* d_ws, size_t ws_size,
                              hipStream_t stream) {
    const float* X         = (const float*)d_in[0];
    const float* w1        = (const float*)d_in[1];
    const float* bn_scale  = (const float*)d_in[2];
    const float* bn_bias   = (const float*)d_in[3];
    const float* bn_mean   = (const float*)d_in[4];
    const float* bn_var    = (const float*)d_in[5];
    const float* w2        = (const float*)d_in[6];
    const float* a0_raw    = (const float*)d_in[7];
    const float* sigma_raw = (const float*)d_in[8];
    float* out = (float*)d_out;
    float* ws  = (float*)d_ws;

    float* par = ws;                       // 4096 floats (params)
    float* S   = ws + 4096;                // B*K*HW = 262144 floats

    prep_kernel<<<1, 256, 0, stream>>>(w1, bn_scale, bn_bias, bn_mean, bn_var,
                                       w2, a0_raw, sigma_raw, par);

    int n1 = B_ * K_ * HW_ * 2;            // 524288 threads (2 per pixel)
    stage1_kernel<<<n1 / 256, 256, 0, stream>>>(X, par, par + 2048, par + 2080, S);

    int n2 = B_ * HW_ / TILE_;             // 1024 blocks
    capon_fuse_kernel<<<n2, 256, 0, stream>>>(X, S, par + 2112, par + 2120, out);
}